// Round 3
// baseline (1851.781 us; speedup 1.0000x reference)
//
#include <hip/hip_runtime.h>
#include <math.h>

#define N_NODES 10000
#define N_EDGES 160000
#define BATCH 32
#define HLEN 12
#define KORD 25
#define G1 32
#define NCLS 10
#define BH 384   /* BATCH*HLEN */
#define BG 1024  /* BATCH*G1  */

// ---------------- CSR build ----------------
__global__ void deg_kernel(const int* __restrict__ row, int* __restrict__ cnt) {
    int e = blockIdx.x * 256 + threadIdx.x;
    if (e < N_EDGES) atomicAdd(&cnt[row[e]], 1);
}

__global__ void dinv_kernel(const int* __restrict__ cnt, float* __restrict__ dinv) {
    int n = blockIdx.x * 256 + threadIdx.x;
    if (n < N_NODES) {
        int d = cnt[n];
        dinv[n] = (d > 0) ? 1.0f / sqrtf((float)d) : 0.0f;
    }
}

__global__ __launch_bounds__(1024) void scan_kernel(const int* __restrict__ cnt,
                                                    int* __restrict__ rowstart) {
    __shared__ int sums[1024];
    int t = threadIdx.x;
    const int per = 10; // 1024*10 >= 10000
    int base = t * per;
    int s = 0;
    for (int i = 0; i < per; i++) { int idx = base + i; if (idx < N_NODES) s += cnt[idx]; }
    sums[t] = s;
    __syncthreads();
    for (int off = 1; off < 1024; off <<= 1) {
        int v = 0;
        if (t >= off) v = sums[t - off];
        __syncthreads();
        sums[t] += v;
        __syncthreads();
    }
    int run = sums[t] - s; // exclusive prefix for this chunk
    for (int i = 0; i < per; i++) {
        int idx = base + i;
        if (idx < N_NODES) { rowstart[idx] = run; run += cnt[idx]; }
    }
    if (t == 1023) rowstart[N_NODES] = run;
}

__global__ void scatter_kernel(const int* __restrict__ row, const int* __restrict__ col,
                               const float* __restrict__ dinv,
                               const int* __restrict__ rowstart, int* __restrict__ cursor,
                               int* __restrict__ csr_col, float* __restrict__ csr_norm) {
    int e = blockIdx.x * 256 + threadIdx.x;
    if (e < N_EDGES) {
        int r = row[e], c = col[e];
        int p = rowstart[r] + atomicAdd(&cursor[r], 1);
        csr_col[p] = c;
        csr_norm[p] = -dinv[r] * dinv[c];
    }
}

// ---------------- FFT (real part, H=12 cosine transform) ----------------
// x: [B, N, H] b-major.  xf: [N, B*H] node-major.
__global__ __launch_bounds__(256) void fft_kernel(const float* __restrict__ x,
                                                  float* __restrict__ xf) {
    __shared__ float C[HLEN][HLEN];
    int t = threadIdx.x;
    if (t < HLEN * HLEN) {
        int k = t / HLEN, tt = t % HLEN;
        C[k][tt] = cosf(0.52359877559829887308f * (float)(k * tt)); // pi/6 * k*t
    }
    __syncthreads();
    int tid = blockIdx.x * 256 + t; // tid = n*32 + b
    if (tid >= N_NODES * BATCH) return;
    int n = tid >> 5, b = tid & 31;
    const float* xp = x + (size_t)b * (N_NODES * HLEN) + (size_t)n * HLEN;
    float xr[HLEN];
#pragma unroll
    for (int i = 0; i < HLEN; i++) xr[i] = xp[i];
    float* o = xf + (size_t)n * BH + b * HLEN;
#pragma unroll
    for (int k = 0; k < HLEN; k++) {
        float s = 0.f;
#pragma unroll
        for (int i = 0; i < HLEN; i++) s += xr[i] * C[k][i];
        o[k] = s;
    }
}

// ---------------- pure SpMM: znext = alpha*(Lt @ zcur) - beta*zprev ----------------
// No LDS, no barriers, no weights. One node per wave, 4 nodes per 256-block.
__global__ __launch_bounds__(256) void spmm_kernel(
    const float* __restrict__ zcur, const float* __restrict__ zprev,
    float* __restrict__ znext,
    const int* __restrict__ rowstart, const int* __restrict__ csr_col,
    const float* __restrict__ csr_norm, float alpha, float beta) {
    int t = threadIdx.x;
    int wv = t >> 6, lane = t & 63;
    int node = blockIdx.x * 4 + wv;

    float4 a4 = {0.f, 0.f, 0.f, 0.f};
    float2 a2 = {0.f, 0.f};
    int e0 = rowstart[node], e1 = rowstart[node + 1];
    int e = e0;
    for (; e + 2 <= e1; e += 2) {
        int c0 = csr_col[e], c1 = csr_col[e + 1];
        float n0 = csr_norm[e], n1 = csr_norm[e + 1];
        const float* z0 = zcur + (size_t)c0 * BH;
        const float* z1 = zcur + (size_t)c1 * BH;
        float4 x0 = *(const float4*)(z0 + 4 * lane);
        float2 y0 = *(const float2*)(z0 + 256 + 2 * lane);
        float4 x1 = *(const float4*)(z1 + 4 * lane);
        float2 y1 = *(const float2*)(z1 + 256 + 2 * lane);
        a4.x += n0 * x0.x + n1 * x1.x;
        a4.y += n0 * x0.y + n1 * x1.y;
        a4.z += n0 * x0.z + n1 * x1.z;
        a4.w += n0 * x0.w + n1 * x1.w;
        a2.x += n0 * y0.x + n1 * y1.x;
        a2.y += n0 * y0.y + n1 * y1.y;
    }
    if (e < e1) {
        int c0 = csr_col[e];
        float n0 = csr_norm[e];
        const float* z0 = zcur + (size_t)c0 * BH;
        float4 x0 = *(const float4*)(z0 + 4 * lane);
        float2 y0 = *(const float2*)(z0 + 256 + 2 * lane);
        a4.x += n0 * x0.x; a4.y += n0 * x0.y;
        a4.z += n0 * x0.z; a4.w += n0 * x0.w;
        a2.x += n0 * y0.x; a2.y += n0 * y0.y;
    }
    const float* pv = zprev + (size_t)node * BH;
    float4 p4 = *(const float4*)(pv + 4 * lane);
    float2 p2 = *(const float2*)(pv + 256 + 2 * lane);
    float4 v4; float2 v2;
    v4.x = alpha * a4.x - beta * p4.x;
    v4.y = alpha * a4.y - beta * p4.y;
    v4.z = alpha * a4.z - beta * p4.z;
    v4.w = alpha * a4.w - beta * p4.w;
    v2.x = alpha * a2.x - beta * p2.x;
    v2.y = alpha * a2.y - beta * p2.y;
    float* nx = znext + (size_t)node * BH;
    *(float4*)(nx + 4 * lane) = v4;
    *(float2*)(nx + 256 + 2 * lane) = v2;
}

// ---------------- one-shot einsum over all k: out[n] = sum_k T_k[n] @ W_k ----------------
// No LDS, no barriers. Wave = node. lane -> (g = lane>>3, s = lane&7); f-quad = 4s,
// b = g + 8r (r=0..3). Weights broadcast via L1.
__global__ __launch_bounds__(256) void einsum_all_kernel(
    const float* __restrict__ T_all,   // [KORD][N_NODES][BH]
    const float* __restrict__ conv_w,  // [KORD][HLEN][G1]
    float* __restrict__ out) {         // [N_NODES][BG]
    int t = threadIdx.x;
    int wv = t >> 6, lane = t & 63;
    int node = blockIdx.x * 4 + wv;
    int g = lane >> 3, s = lane & 7;
    int f0 = 4 * s;

    float4 acc[4];
#pragma unroll
    for (int r = 0; r < 4; r++) acc[r] = make_float4(0.f, 0.f, 0.f, 0.f);

    for (int k = 0; k < KORD; k++) {
        const float* wk = conv_w + (size_t)k * (HLEN * G1) + f0;
        float4 w[HLEN];
#pragma unroll
        for (int h = 0; h < HLEN; h++) w[h] = *(const float4*)(wk + h * G1);
        const float* zn = T_all + (size_t)k * ((size_t)N_NODES * BH) + (size_t)node * BH;
#pragma unroll
        for (int r = 0; r < 4; r++) {
            int b = g + 8 * r;
            const float* zb = zn + b * HLEN;
            float4 z0 = *(const float4*)(zb);
            float4 z1 = *(const float4*)(zb + 4);
            float4 z2 = *(const float4*)(zb + 8);
            float zr[HLEN] = {z0.x, z0.y, z0.z, z0.w,
                              z1.x, z1.y, z1.z, z1.w,
                              z2.x, z2.y, z2.z, z2.w};
#pragma unroll
            for (int h = 0; h < HLEN; h++) {
                acc[r].x += zr[h] * w[h].x;
                acc[r].y += zr[h] * w[h].y;
                acc[r].z += zr[h] * w[h].z;
                acc[r].w += zr[h] * w[h].w;
            }
        }
    }
    float* op = out + (size_t)node * BG;
#pragma unroll
    for (int r = 0; r < 4; r++) {
        int b = g + 8 * r;
        *(float4*)(op + b * G1 + f0) = acc[r];
    }
}

// ---------------- FALLBACK (ws too small): fused prop + einsum accumulate ----------------
__global__ __launch_bounds__(256) void k0_kernel(const float* __restrict__ z,
                                                 float* __restrict__ out,
                                                 const float* __restrict__ w0) {
    __shared__ __align__(16) float lds[4][BH];
    __shared__ float wk[BH];
    int t = threadIdx.x;
    for (int i = t; i < BH; i += 256) wk[i] = w0[i];
    int wv = t >> 6, lane = t & 63;
    int node = blockIdx.x * 4 + wv;
    const float* zp = z + (size_t)node * BH;
    float4 z4 = *(const float4*)(zp + 4 * lane);
    float2 z2 = *(const float2*)(zp + 256 + 2 * lane);
    *(float4*)(&lds[wv][4 * lane]) = z4;
    *(float2*)(&lds[wv][256 + 2 * lane]) = z2;
    __syncthreads();
    float* op = out + (size_t)node * BG;
#pragma unroll
    for (int r = 0; r < 4; r++) {
        int idx = 4 * lane + 256 * r;
        int b = idx >> 5;
        int f0 = idx & 31;
        const float* zb = &lds[wv][b * HLEN];
        float4 sv = {0.f, 0.f, 0.f, 0.f};
#pragma unroll
        for (int h = 0; h < HLEN; h++) {
            float zv = zb[h];
            sv.x += zv * wk[h * G1 + f0 + 0];
            sv.y += zv * wk[h * G1 + f0 + 1];
            sv.z += zv * wk[h * G1 + f0 + 2];
            sv.w += zv * wk[h * G1 + f0 + 3];
        }
        *(float4*)(op + idx) = sv;
    }
}

__global__ __launch_bounds__(256) void prop_kernel(
    const float* __restrict__ zcur, const float* __restrict__ zprev,
    float* __restrict__ znext, float* __restrict__ out,
    const int* __restrict__ rowstart, const int* __restrict__ csr_col,
    const float* __restrict__ csr_norm, const float* __restrict__ wkg,
    float alpha, float beta) {
    __shared__ __align__(16) float lds[4][BH];
    __shared__ float wk[BH];
    int t = threadIdx.x;
    for (int i = t; i < BH; i += 256) wk[i] = wkg[i];
    int wv = t >> 6, lane = t & 63;
    int node = blockIdx.x * 4 + wv;

    float4 a4 = {0.f, 0.f, 0.f, 0.f};
    float2 a2 = {0.f, 0.f};
    int e0 = rowstart[node], e1 = rowstart[node + 1];
    for (int e = e0; e < e1; e++) {
        int c = csr_col[e];
        float nrm = csr_norm[e];
        const float* zp = zcur + (size_t)c * BH;
        float4 z4 = *(const float4*)(zp + 4 * lane);
        float2 z2 = *(const float2*)(zp + 256 + 2 * lane);
        a4.x += nrm * z4.x; a4.y += nrm * z4.y;
        a4.z += nrm * z4.z; a4.w += nrm * z4.w;
        a2.x += nrm * z2.x; a2.y += nrm * z2.y;
    }
    const float* pv = zprev + (size_t)node * BH;
    float4 p4 = *(const float4*)(pv + 4 * lane);
    float2 p2 = *(const float2*)(pv + 256 + 2 * lane);
    float4 v4; float2 v2;
    v4.x = alpha * a4.x - beta * p4.x;
    v4.y = alpha * a4.y - beta * p4.y;
    v4.z = alpha * a4.z - beta * p4.z;
    v4.w = alpha * a4.w - beta * p4.w;
    v2.x = alpha * a2.x - beta * p2.x;
    v2.y = alpha * a2.y - beta * p2.y;
    float* nx = znext + (size_t)node * BH;
    *(float4*)(nx + 4 * lane) = v4;
    *(float2*)(nx + 256 + 2 * lane) = v2;
    *(float4*)(&lds[wv][4 * lane]) = v4;
    *(float2*)(&lds[wv][256 + 2 * lane]) = v2;
    __syncthreads();
    float* op = out + (size_t)node * BG;
#pragma unroll
    for (int r = 0; r < 4; r++) {
        int idx = 4 * lane + 256 * r;
        int b = idx >> 5;
        int f0 = idx & 31;
        const float* zb = &lds[wv][b * HLEN];
        float4 sv = {0.f, 0.f, 0.f, 0.f};
#pragma unroll
        for (int h = 0; h < HLEN; h++) {
            float zv = zb[h];
            sv.x += zv * wk[h * G1 + f0 + 0];
            sv.y += zv * wk[h * G1 + f0 + 1];
            sv.z += zv * wk[h * G1 + f0 + 2];
            sv.w += zv * wk[h * G1 + f0 + 3];
        }
        float4 cur = *(const float4*)(op + idx);
        cur.x += sv.x; cur.y += sv.y; cur.z += sv.z; cur.w += sv.w;
        *(float4*)(op + idx) = cur;
    }
}

// ---------------- FC: logits[b,c] = sum_{n,f} relu(out + cb) * fc_w ----------------
__global__ __launch_bounds__(1024) void fc_kernel(const float* __restrict__ out,
                                                  const float* __restrict__ conv_b,
                                                  const float* __restrict__ fc_w,
                                                  float* __restrict__ logits) {
    int t = threadIdx.x;
    int lane = t & 63;
    int b = t >> 5;        // 0..31
    int f = t & 31;        // 0..31
    float cbf = conv_b[f];

    const int nodes_per = (N_NODES + gridDim.x - 1) / gridDim.x;
    int n0 = blockIdx.x * nodes_per;
    int n1 = n0 + nodes_per;
    if (n1 > N_NODES) n1 = N_NODES;

    float acc[NCLS];
#pragma unroll
    for (int c = 0; c < NCLS; c++) acc[c] = 0.f;

    int n = n0;
    for (; n + 2 <= n1; n += 2) {
        float h0 = out[(size_t)n * BG + t] + cbf;
        float h1 = out[(size_t)(n + 1) * BG + t] + cbf;
        h0 = h0 > 0.f ? h0 : 0.f;
        h1 = h1 > 0.f ? h1 : 0.f;
        const float* wp0 = fc_w + (size_t)n * G1 + f;
        const float* wp1 = wp0 + G1;
#pragma unroll
        for (int c = 0; c < NCLS; c++) {
            size_t co = (size_t)c * (N_NODES * G1);
            acc[c] += h0 * wp0[co] + h1 * wp1[co];
        }
    }
    for (; n < n1; n++) {
        float h0 = out[(size_t)n * BG + t] + cbf;
        h0 = h0 > 0.f ? h0 : 0.f;
        const float* wp0 = fc_w + (size_t)n * G1 + f;
#pragma unroll
        for (int c = 0; c < NCLS; c++)
            acc[c] += h0 * wp0[(size_t)c * (N_NODES * G1)];
    }
#pragma unroll
    for (int c = 0; c < NCLS; c++) {
        float v = acc[c];
        v += __shfl_xor(v, 1);
        v += __shfl_xor(v, 2);
        v += __shfl_xor(v, 4);
        v += __shfl_xor(v, 8);
        v += __shfl_xor(v, 16);
        if ((lane & 31) == 0) atomicAdd(&logits[b * NCLS + c], v);
    }
}

__global__ void softmax_kernel(const float* __restrict__ logits,
                               const float* __restrict__ fc_b,
                               float* __restrict__ out) {
    int b = threadIdx.x;
    if (b < BATCH) {
        float v[NCLS];
        float m = -1e30f;
#pragma unroll
        for (int c = 0; c < NCLS; c++) {
            v[c] = logits[b * NCLS + c] + fc_b[c];
            m = fmaxf(m, v[c]);
        }
        float s = 0.f;
#pragma unroll
        for (int c = 0; c < NCLS; c++) s += expf(v[c] - m);
        float ls = logf(s);
#pragma unroll
        for (int c = 0; c < NCLS; c++) out[b * NCLS + c] = v[c] - m - ls;
    }
}

extern "C" void kernel_launch(void* const* d_in, const int* in_sizes, int n_in,
                              void* d_out, int out_size, void* d_ws, size_t ws_size,
                              hipStream_t stream) {
    const float* x      = (const float*)d_in[0];
    const int*   ei     = (const int*)d_in[1];
    const float* conv_w = (const float*)d_in[2];
    const float* conv_b = (const float*)d_in[3];
    const float* fc_w   = (const float*)d_in[4];
    const float* fc_b   = (const float*)d_in[5];
    float* outp = (float*)d_out;

    const int* row = ei;
    const int* col = ei + N_EDGES;

    const size_t SLAB = (size_t)N_NODES * BH; // floats per T slab

    char* ws = (char*)d_ws;
    size_t off = 0;
    auto alloc = [&](size_t bytes) -> void* {
        void* p = ws + off;
        off = (off + bytes + 255) & ~(size_t)255;
        return p;
    };
    // common small buffers first
    float* outacc   = (float*)alloc(sizeof(float) * (size_t)N_NODES * BG);
    int*   cnt      = (int*)alloc(sizeof(int) * N_NODES);
    float* dinv     = (float*)alloc(sizeof(float) * N_NODES);
    int*   rowstart = (int*)alloc(sizeof(int) * (N_NODES + 1));
    int*   cursor   = (int*)alloc(sizeof(int) * N_NODES);
    int*   csr_col  = (int*)alloc(sizeof(int) * N_EDGES);
    float* csr_norm = (float*)alloc(sizeof(float) * N_EDGES);
    float* logits   = (float*)alloc(sizeof(float) * BATCH * NCLS);
    size_t fixed_off = off;

    bool big_path = (ws_size >= fixed_off + sizeof(float) * SLAB * KORD + 4096);

    hipMemsetAsync(cnt, 0, sizeof(int) * N_NODES, stream);
    hipMemsetAsync(cursor, 0, sizeof(int) * N_NODES, stream);
    hipMemsetAsync(logits, 0, sizeof(float) * BATCH * NCLS, stream);

    deg_kernel<<<(N_EDGES + 255) / 256, 256, 0, stream>>>(row, cnt);
    dinv_kernel<<<(N_NODES + 255) / 256, 256, 0, stream>>>(cnt, dinv);
    scan_kernel<<<1, 1024, 0, stream>>>(cnt, rowstart);
    scatter_kernel<<<(N_EDGES + 255) / 256, 256, 0, stream>>>(row, col, dinv, rowstart,
                                                              cursor, csr_col, csr_norm);

    if (big_path) {
        float* T_all = (float*)alloc(sizeof(float) * SLAB * KORD);
        // T0 = xf
        fft_kernel<<<(N_NODES * BATCH + 255) / 256, 256, 0, stream>>>(x, T_all);
        // T1 = Lt T0
        spmm_kernel<<<N_NODES / 4, 256, 0, stream>>>(T_all, T_all, T_all + SLAB,
                                                     rowstart, csr_col, csr_norm,
                                                     1.0f, 0.0f);
        // Tk = 2 Lt T_{k-1} - T_{k-2}
        for (int k = 2; k < KORD; k++) {
            spmm_kernel<<<N_NODES / 4, 256, 0, stream>>>(
                T_all + SLAB * (size_t)(k - 1), T_all + SLAB * (size_t)(k - 2),
                T_all + SLAB * (size_t)k, rowstart, csr_col, csr_norm, 2.0f, 1.0f);
        }
        einsum_all_kernel<<<N_NODES / 4, 256, 0, stream>>>(T_all, conv_w, outacc);
    } else {
        float* buf0 = (float*)alloc(sizeof(float) * SLAB);
        float* buf1 = (float*)alloc(sizeof(float) * SLAB);
        fft_kernel<<<(N_NODES * BATCH + 255) / 256, 256, 0, stream>>>(x, buf0);
        k0_kernel<<<N_NODES / 4, 256, 0, stream>>>(buf0, outacc, conv_w);
        prop_kernel<<<N_NODES / 4, 256, 0, stream>>>(buf0, buf0, buf1, outacc, rowstart,
                                                     csr_col, csr_norm, conv_w + 1 * BH,
                                                     1.0f, 0.0f);
        float* zprev = buf0;
        float* zcur  = buf1;
        for (int k = 2; k < KORD; k++) {
            prop_kernel<<<N_NODES / 4, 256, 0, stream>>>(zcur, zprev, zprev, outacc,
                                                         rowstart, csr_col, csr_norm,
                                                         conv_w + (size_t)k * BH,
                                                         2.0f, 1.0f);
            float* tmp = zprev; zprev = zcur; zcur = tmp;
        }
    }

    fc_kernel<<<625, 1024, 0, stream>>>(outacc, conv_b, fc_w, logits);
    softmax_kernel<<<1, 64, 0, stream>>>(logits, fc_b, outp);
}